// Round 14
// baseline (284.403 us; speedup 1.0000x reference)
//
#include <hip/hip_runtime.h>

// ---------------------------------------------------------------------------
// sLSTM cell, B=8192, D=1024, H=1024.
//   pre[B,4H] = [x,h_prev] @ [Wg|Rg]^T  (K = D+H = 2048)
//   i=exp(pi+bi), f=sig(pf+bf), o=sig(po+bo), z=tanh(pz+bz)
//   c=f*c_prev+i*z ; n=f*n_prev+i ; m=max(log f + m_prev, pi) ; h=o*c/n
//   outputs (flat): h, c, C_prev(copy), n, m  -- each B*H f32
//
// Round 14: 256x128 block tile, 8 waves (4M x 2N), SAME proven 64x64
// per-wave shape and 2-barrier K-loop as R2/R10.
//   - LDS single tile: lA 256x64 (32KB) + lB 128x64 (16KB) = 48KB.
//   - __launch_bounds__(512,4): unified regs <=128 -> VGPR <=64 (R1-proven
//     budget) -> 2 blocks/CU x 8 waves = 16 waves/CU (vs 12 at R10, +33%).
//   - Block generations halve (1024 blocks -> 512 slots -> 2 gens), halving
//     the per-block epilogue-tail exposure that fusion added.
//   - Epilogue: c/n/m staged into the 48KB overlay in TWO half-batches
//     (each exactly 48KB), one vmcnt(0) per half. No store-count vmcnt
//     arithmetic -> strictly race-free.
// Gate-interleaved W packing: packed row r -> gate (r>>4)&3,
// j=(r>>6)*16+(r&15) => a wave's 4 N-frags are {pi,pf,po,pz} of the same j.
// ---------------------------------------------------------------------------

#define B_SZ 8192
#define D_SZ 1024
#define H_SZ 1024
#define K_SZ 2048   // D + H
#define N4H  4096   // 4*H

typedef __attribute__((ext_vector_type(4))) float f32x4;
typedef _Float16 f16;
typedef __attribute__((ext_vector_type(8))) f16 f16x8;
typedef unsigned short u16;
typedef __attribute__((ext_vector_type(4))) unsigned short u16x4;

static __device__ __forceinline__ u16 f2h(float f) {
    f16 h = (f16)f;
    return __builtin_bit_cast(unsigned short, h);
}

static __device__ __forceinline__ float rcp_fast(float x) {
    float r;
    asm("v_rcp_f32 %0, %1" : "=v"(r) : "v"(x));
    return r;
}

static __device__ __forceinline__ void load_lds16(const void* g, void* l) {
    __builtin_amdgcn_global_load_lds(
        (const __attribute__((address_space(1))) void*)g,
        (__attribute__((address_space(3))) void*)l, 16, 0, 0);
}

// ---------------------------------------------------------------------------
// Merged pack + passthrough kernel (identical to R9/R10/R13).
// ---------------------------------------------------------------------------
__global__ void convert_AW(const float* __restrict__ x, const float* __restrict__ h,
                           const float* __restrict__ Wi, const float* __restrict__ Wf,
                           const float* __restrict__ Wo, const float* __restrict__ Wz,
                           const float* __restrict__ Ri, const float* __restrict__ Rf,
                           const float* __restrict__ Ro, const float* __restrict__ Rz,
                           const float* __restrict__ C_prev,
                           u16* __restrict__ A, u16* __restrict__ Wb,
                           float* __restrict__ outC) {
    const size_t nvecA = (size_t)B_SZ * K_SZ / 4;
    const size_t nvecW = (size_t)N4H * K_SZ / 4;
    const size_t nvecC = (size_t)B_SZ * H_SZ / 4;
    const size_t nvec  = nvecA + nvecW + nvecC;
    const size_t stride = (size_t)gridDim.x * blockDim.x;
    for (size_t v = (size_t)blockIdx.x * blockDim.x + threadIdx.x; v < nvec; v += stride) {
        if (v >= nvecA + nvecW) {
            size_t e = (v - nvecA - nvecW) * 4;
            *(f32x4*)&outC[e] = *(const f32x4*)&C_prev[e];
            continue;
        }
        const float* src;
        u16* dst;
        if (v < nvecA) {
            size_t e = v * 4;
            size_t row = e >> 11;
            int col = (int)(e & 2047);
            src = (col < D_SZ) ? (x + row * D_SZ + col)
                               : (h + row * H_SZ + (col - D_SZ));
            dst = A + e;
        } else {
            size_t e = (v - nvecA) * 4;
            size_t r = e >> 11;                 // packed row 0..4095
            int col = (int)(e & 2047);
            int g = (int)(r >> 4) & 3;          // gate
            int j = (int)((r >> 6) << 4) | (int)(r & 15);
            const float* Wg = (g == 0) ? Wi : (g == 1) ? Wf : (g == 2) ? Wo : Wz;
            const float* Rg = (g == 0) ? Ri : (g == 1) ? Rf : (g == 2) ? Ro : Rz;
            src = (col < D_SZ) ? (Wg + (size_t)j * D_SZ + col)
                               : (Rg + (size_t)j * H_SZ + (col - D_SZ));
            dst = Wb + e;
        }
        f32x4 val = *(const f32x4*)src;
        u16x4 o;
        o[0] = f2h(val[0]); o[1] = f2h(val[1]); o[2] = f2h(val[2]); o[3] = f2h(val[3]);
        *(u16x4*)dst = o;
    }
}

// ---------------------------------------------------------------------------
// Fused GEMM + sLSTM epilogue. 512 threads, 8 waves (4M x 2N), 256x128 tile,
// BK=64, per-wave 64x64 (acc 4x4), 2-barrier K-loop.
// ---------------------------------------------------------------------------
__global__ __launch_bounds__(512, 4)
void gemm_fused(const u16* __restrict__ A, const u16* __restrict__ W,
                const float* __restrict__ c_prev, const float* __restrict__ n_prev,
                const float* __restrict__ m_prev,
                const float* __restrict__ bi, const float* __restrict__ bfv,
                const float* __restrict__ bo, const float* __restrict__ bz,
                float* __restrict__ out) {
    __shared__ char smem[49152];                 // 48KB
    u16* lA = (u16*)smem;                        // 32KB: A tile 256x64
    u16* lB = (u16*)(smem + 32768);              // 16KB: B tile 128x64
    // epilogue overlay (after final barrier): 3 arrays x 16KB; per wave 2KB.
    // half-batch hh covers rows [wm*64 + hh*32, +32).

    const int tid = threadIdx.x;
    const int w  = tid >> 6;       // wave 0..7
    const int l  = tid & 63;       // lane
    const int wm = w >> 1;         // M-wave 0..3 (64 rows each)
    const int wn = w & 1;          // N-wave 0..1 (64 packed cols each)
    const int m0 = blockIdx.x * 256;
    const int n0 = blockIdx.y * 128;

    const int lrow8 = l >> 3;            // row within the wave's 8-row stripe
    const int lseg  = (l & 7) ^ lrow8;   // pre-swizzled global 16B-segment index

    const int fr = l & 15;   // fragment row (M for A, N for B), also C col
    const int kq = l >> 4;   // k-quad 0..3

    f32x4 acc[4][4] = {};

    auto stage = [&](int kt) {
#pragma unroll
        for (int r = 0; r < 4; ++r) {                        // A: 256 rows
            int row = r * 64 + w * 8 + lrow8;
            const u16* gA = A + (size_t)(m0 + row) * K_SZ + kt + lseg * 8;
            load_lds16(gA, (char*)lA + (r * 64 + w * 8) * 128);
        }
#pragma unroll
        for (int r = 0; r < 2; ++r) {                        // B: 128 rows
            int row = r * 64 + w * 8 + lrow8;
            const u16* gB = W + (size_t)(n0 + row) * K_SZ + kt + lseg * 8;
            load_lds16(gB, (char*)lB + (r * 64 + w * 8) * 128);
        }
    };

    auto compute = [&]() {
#pragma unroll
        for (int ks = 0; ks < 2; ++ks) {
            f16x8 af[4], bfr[4];
#pragma unroll
            for (int mi = 0; mi < 4; ++mi) {
                int row = wm * 64 + mi * 16 + fr;            // 0..255
                int seg = (ks * 4 + kq) ^ (row & 7);
                af[mi] = *(const f16x8*)&lA[row * 64 + seg * 8];
            }
#pragma unroll
            for (int ni = 0; ni < 4; ++ni) {
                int row = wn * 64 + ni * 16 + fr;            // 0..127
                int seg = (ks * 4 + kq) ^ (row & 7);
                bfr[ni] = *(const f16x8*)&lB[row * 64 + seg * 8];
            }
#pragma unroll
            for (int mi = 0; mi < 4; ++mi)
#pragma unroll
                for (int ni = 0; ni < 4; ++ni)
                    acc[mi][ni] = __builtin_amdgcn_mfma_f32_16x16x32_f16(
                        af[mi], bfr[ni], acc[mi][ni], 0, 0, 0);
        }
    };

    // ---- main K-loop (R2-style 2-barrier schedule) -----------------------
    for (int kt = 0; kt < K_SZ; kt += 64) {
        stage(kt);
        __syncthreads();
        compute();
        __syncthreads();
    }
    // lA/lB dead; vmcnt drained by the final barrier.

    // ---- epilogue: c/n/m staged in two half-batches (48KB overlay) -------
    const int jbase = ((n0 + wn * 64) >> 6) * 16;
    const size_t lsrc = (size_t)(l >> 2) * H_SZ + (l & 3) * 4;
    const size_t gbase = (size_t)(m0 + wm * 64) * H_SZ + jbase;

    auto issueHalf = [&](int hh) {
        const size_t s0 = gbase + (size_t)hh * 32 * H_SZ + lsrc;
#pragma unroll
        for (int k = 0; k < 2; ++k) {
            const size_t s = s0 + (size_t)k * 16 * H_SZ;
            load_lds16(c_prev + s, smem +     0 + w * 2048 + k * 1024);
            load_lds16(n_prev + s, smem + 16384 + w * 2048 + k * 1024);
            load_lds16(m_prev + s, smem + 32768 + w * 2048 + k * 1024);
        }
    };

    issueHalf(0);
    const int j = jbase + fr;                          // 0..1023
    const float bvi = bi[j], bvf = bfv[j], bvo = bo[j], bvz = bz[j];

    const size_t BH = (size_t)B_SZ * H_SZ;
    const float* eC = (const float*)(smem);
    const float* eN = (const float*)(smem + 16384);
    const float* eM = (const float*)(smem + 32768);
    const int ebase = w * 512;                         // float idx of wave panel

    auto epiRound = [&](int mi) {
        const int mi2 = mi & 1;                        // row block within half
        const int rbase = m0 + wm * 64 + mi * 16 + kq * 4;
#pragma unroll
        for (int r2 = 0; r2 < 4; ++r2) {
            const size_t idx = (size_t)(rbase + r2) * H_SZ + j;
            const int eidx = ebase + (mi2 * 16 + kq * 4 + r2) * 16 + fr;
            float pi = acc[mi][0][r2] + bvi;
            float pf = acc[mi][1][r2] + bvf;
            float po = acc[mi][2][r2] + bvo;
            float pz = acc[mi][3][r2] + bvz;
            float iv = __expf(pi);
            float fv = rcp_fast(1.0f + __expf(-pf));                     // sigmoid
            float ov = rcp_fast(1.0f + __expf(-po));                     // sigmoid
            float zv = 1.0f - 2.0f * rcp_fast(__expf(2.0f * pz) + 1.0f); // tanh
            float cv = fv * eC[eidx] + iv * zv;
            float nv = fv * eN[eidx] + iv;
            float mv = fmaxf(__logf(fv) + eM[eidx], pi);
            out[idx]          = ov * cv * rcp_fast(nv);                  // h
            out[BH + idx]     = cv;                                      // c
            out[3 * BH + idx] = nv;                                      // n
            out[4 * BH + idx] = mv;                                      // m
        }
    };

    asm volatile("s_waitcnt vmcnt(0)" ::: "memory");   // half0 + bias landed
    epiRound(0);
    epiRound(1);
    // half0 panels consumed by THIS wave only (wave-private regions) -> safe
    // to overwrite without a block barrier.
    issueHalf(1);
    asm volatile("s_waitcnt vmcnt(0)" ::: "memory");   // half1 landed
    epiRound(2);
    epiRound(3);
}

// ---------------------------------------------------------------------------
extern "C" void kernel_launch(void* const* d_in, const int* in_sizes, int n_in,
                              void* d_out, int out_size, void* d_ws, size_t ws_size,
                              hipStream_t stream) {
    const float* x      = (const float*)d_in[0];
    const float* h_prev = (const float*)d_in[1];
    const float* c_prev = (const float*)d_in[2];
    const float* C_prev = (const float*)d_in[3];
    const float* n_prev = (const float*)d_in[4];
    const float* m_prev = (const float*)d_in[5];
    const float* Wz = (const float*)d_in[6];
    const float* bz = (const float*)d_in[7];
    const float* Rz = (const float*)d_in[8];
    const float* Wi = (const float*)d_in[9];
    const float* bi = (const float*)d_in[10];
    const float* Ri = (const float*)d_in[11];
    const float* Wf = (const float*)d_in[12];
    const float* bf = (const float*)d_in[13];
    const float* Rf = (const float*)d_in[14];
    const float* Wo = (const float*)d_in[15];
    const float* bo = (const float*)d_in[16];
    const float* Ro = (const float*)d_in[17];
    float* out = (float*)d_out;

    const size_t BH = (size_t)B_SZ * H_SZ;

    // workspace layout: A_f16 (32MB) | W_f16 (16MB)
    u16* Abuf = (u16*)d_ws;
    u16* Wbuf = (u16*)((char*)d_ws + (size_t)32 * 1024 * 1024);

    convert_AW<<<2048, 256, 0, stream>>>(x, h_prev, Wi, Wf, Wo, Wz,
                                         Ri, Rf, Ro, Rz, C_prev,
                                         Abuf, Wbuf, out + 2 * BH);

    gemm_fused<<<dim3(B_SZ / 256, N4H / 128), 512, 0, stream>>>(
        Abuf, Wbuf, c_prev, n_prev, m_prev, bi, bf, bo, bz, out);
}

// Round 15
// 206.564 us; speedup vs baseline: 1.3768x; 1.3768x over previous
//
#include <hip/hip_runtime.h>

// ---------------------------------------------------------------------------
// sLSTM cell, B=8192, D=1024, H=1024.
//   pre[B,4H] = [x,h_prev] @ [Wg|Rg]^T  (K = D+H = 2048)
//   i=exp(pi+bi), f=sig(pf+bf), o=sig(po+bo), z=tanh(pz+bz)
//   c=f*c_prev+i*z ; n=f*n_prev+i ; m=max(log f + m_prev, pi) ; h=o*c/n
//   outputs (flat): h, c, C_prev(copy), n, m  -- each B*H f32
//
// Round 15: REVERT to Round 13 verbatim -- the measured session best
// (208.5us total; gemm ~181us profiled, MfmaUtil ~34%, absmax 0.25).
// R14's 256x128 tile caused 3x HBM write amplification (partial 128B output
// lines evicted from the 4MB/XCD L2 before the partner wave's half landed)
// and is abandoned. Structure summary of this final kernel:
//   - convert_AW: one grid-stride kernel packs A=[x|h_prev] to fp16,
//     W gate-interleaved to fp16, and copies C_prev to out slot 2.
//   - gemm_fused: 128x128 tile, BK=64, 4 waves (2x2) of 64x64, fp16 MFMA
//     16x16x32, XOR-swizzled LDS (0 bank conflicts), global_load_lds w=16,
//     2-barrier K-loop, 48KB LDS -> 3 blocks/CU. Last K-tile peeled: m_prev
//     panel + biases issued under its barrier drain. Epilogue reads c/n/m
//     from LDS panels, computes gates with rcp_fast, writes h/c/n/m.
// Gate-interleaved W packing: packed row r -> gate (r>>4)&3,
// j=(r>>6)*16+(r&15) => a wave's 4 N-frags are {pi,pf,po,pz} of the same j.
// ---------------------------------------------------------------------------

#define B_SZ 8192
#define D_SZ 1024
#define H_SZ 1024
#define K_SZ 2048   // D + H
#define N4H  4096   // 4*H

typedef __attribute__((ext_vector_type(4))) float f32x4;
typedef _Float16 f16;
typedef __attribute__((ext_vector_type(8))) f16 f16x8;
typedef unsigned short u16;
typedef __attribute__((ext_vector_type(4))) unsigned short u16x4;

static __device__ __forceinline__ u16 f2h(float f) {
    f16 h = (f16)f;
    return __builtin_bit_cast(unsigned short, h);
}

static __device__ __forceinline__ float rcp_fast(float x) {
    float r;
    asm("v_rcp_f32 %0, %1" : "=v"(r) : "v"(x));
    return r;
}

static __device__ __forceinline__ void load_lds16(const void* g, void* l) {
    __builtin_amdgcn_global_load_lds(
        (const __attribute__((address_space(1))) void*)g,
        (__attribute__((address_space(3))) void*)l, 16, 0, 0);
}

// ---------------------------------------------------------------------------
// Merged pack + passthrough kernel.
// ---------------------------------------------------------------------------
__global__ void convert_AW(const float* __restrict__ x, const float* __restrict__ h,
                           const float* __restrict__ Wi, const float* __restrict__ Wf,
                           const float* __restrict__ Wo, const float* __restrict__ Wz,
                           const float* __restrict__ Ri, const float* __restrict__ Rf,
                           const float* __restrict__ Ro, const float* __restrict__ Rz,
                           const float* __restrict__ C_prev,
                           u16* __restrict__ A, u16* __restrict__ Wb,
                           float* __restrict__ outC) {
    const size_t nvecA = (size_t)B_SZ * K_SZ / 4;
    const size_t nvecW = (size_t)N4H * K_SZ / 4;
    const size_t nvecC = (size_t)B_SZ * H_SZ / 4;
    const size_t nvec  = nvecA + nvecW + nvecC;
    const size_t stride = (size_t)gridDim.x * blockDim.x;
    for (size_t v = (size_t)blockIdx.x * blockDim.x + threadIdx.x; v < nvec; v += stride) {
        if (v >= nvecA + nvecW) {
            size_t e = (v - nvecA - nvecW) * 4;
            *(f32x4*)&outC[e] = *(const f32x4*)&C_prev[e];
            continue;
        }
        const float* src;
        u16* dst;
        if (v < nvecA) {
            size_t e = v * 4;
            size_t row = e >> 11;
            int col = (int)(e & 2047);
            src = (col < D_SZ) ? (x + row * D_SZ + col)
                               : (h + row * H_SZ + (col - D_SZ));
            dst = A + e;
        } else {
            size_t e = (v - nvecA) * 4;
            size_t r = e >> 11;                 // packed row 0..4095
            int col = (int)(e & 2047);
            int g = (int)(r >> 4) & 3;          // gate
            int j = (int)((r >> 6) << 4) | (int)(r & 15);
            const float* Wg = (g == 0) ? Wi : (g == 1) ? Wf : (g == 2) ? Wo : Wz;
            const float* Rg = (g == 0) ? Ri : (g == 1) ? Rf : (g == 2) ? Ro : Rz;
            src = (col < D_SZ) ? (Wg + (size_t)j * D_SZ + col)
                               : (Rg + (size_t)j * H_SZ + (col - D_SZ));
            dst = Wb + e;
        }
        f32x4 val = *(const f32x4*)src;
        u16x4 o;
        o[0] = f2h(val[0]); o[1] = f2h(val[1]); o[2] = f2h(val[2]); o[3] = f2h(val[3]);
        *(u16x4*)dst = o;
    }
}

// ---------------------------------------------------------------------------
// Fused GEMM + sLSTM epilogue. 256 threads, 4 waves, 128x128 tile, BK=64.
// K-loop: R2-proven 2-barrier schedule; last tile peeled to hide m-panel +
// bias loads under its barrier drain. Epilogue operands staged to LDS.
// ---------------------------------------------------------------------------
__global__ __launch_bounds__(256, 2)
void gemm_fused(const u16* __restrict__ A, const u16* __restrict__ W,
                const float* __restrict__ c_prev, const float* __restrict__ n_prev,
                const float* __restrict__ m_prev,
                const float* __restrict__ bi, const float* __restrict__ bfv,
                const float* __restrict__ bo, const float* __restrict__ bz,
                float* __restrict__ out) {
    __shared__ char smem[49152];                 // 48KB -> 3 blocks/CU
    u16* lA = (u16*)smem;                        // 16KB (K-loop A tile)
    u16* lB = (u16*)(smem + 16384);              // 16KB (K-loop B tile)
    // epilogue overlays: c/n panels reuse lA/lB space (valid only after the
    // final K-loop barrier); m panel lives in the extra 16KB (NEVER aliases
    // the K-loop tiles, so it can be staged early).
    float* eC = (float*)smem;                    // reuses lA space
    float* eN = (float*)(smem + 16384);          // reuses lB space
    float* eM = (float*)(smem + 32768);          // extra 16KB, K-loop-free

    const int tid = threadIdx.x;
    const int w  = tid >> 6;       // wave 0..3
    const int l  = tid & 63;       // lane
    const int wm = w >> 1;         // wave row (2)
    const int wn = w & 1;          // wave col (2)
    const int m0 = blockIdx.x * 128;
    const int n0 = blockIdx.y * 128;

    const int lrow8 = l >> 3;            // row within the wave's 8-row stripe
    const int lseg  = (l & 7) ^ lrow8;   // pre-swizzled global 16B-segment index

    const int fr = l & 15;   // fragment row (M for A, N for B), also C col
    const int kq = l >> 4;   // k-quad 0..3

    f32x4 acc[4][4] = {};

    auto stage = [&](int kt) {
#pragma unroll
        for (int r = 0; r < 4; ++r) {
            int rowA = r * 32 + w * 8 + lrow8;               // 0..127
            const u16* gA = A + (size_t)(m0 + rowA) * K_SZ + kt + lseg * 8;
            load_lds16(gA, (char*)lA + (r * 32 + w * 8) * 128);
            const u16* gB = W + (size_t)(n0 + rowA) * K_SZ + kt + lseg * 8;
            load_lds16(gB, (char*)lB + (r * 32 + w * 8) * 128);
        }
    };

    auto compute = [&]() {
#pragma unroll
        for (int ks = 0; ks < 2; ++ks) {
            f16x8 af[4], bfr[4];
#pragma unroll
            for (int mi = 0; mi < 4; ++mi) {
                int row = wm * 64 + mi * 16 + fr;
                int seg = (ks * 4 + kq) ^ (row & 7);
                af[mi] = *(const f16x8*)&lA[row * 64 + seg * 8];
            }
#pragma unroll
            for (int ni = 0; ni < 4; ++ni) {
                int row = wn * 64 + ni * 16 + fr;
                int seg = (ks * 4 + kq) ^ (row & 7);
                bfr[ni] = *(const f16x8*)&lB[row * 64 + seg * 8];
            }
#pragma unroll
            for (int mi = 0; mi < 4; ++mi)
#pragma unroll
                for (int ni = 0; ni < 4; ++ni)
                    acc[mi][ni] = __builtin_amdgcn_mfma_f32_16x16x32_f16(
                        af[mi], bfr[ni], acc[mi][ni], 0, 0, 0);
        }
    };

    // epilogue panel geometry: wave (wm,wn) owns rows [m0+wm*64,+64) x cols
    // [jbase,+16).  Per issue k: lane l covers row k*16+(l>>2), 16B (l&3).
    const int jbase = ((n0 + wn * 64) >> 6) * 16;
    const size_t goff = (size_t)(m0 + wm * 64) * H_SZ + jbase;
    const size_t lsrc = (size_t)(l >> 2) * H_SZ + (l & 3) * 4;

    // ---- main K-loop, last tile peeled -----------------------------------
    for (int kt = 0; kt < K_SZ - 64; kt += 64) {
        stage(kt);
        __syncthreads();
        compute();
        __syncthreads();
    }

    // peeled last tile: stage it, then issue the m-panel (region untouched
    // by the K-loop) and bias loads -- all drained for free by the barrier.
    stage(K_SZ - 64);
    {
        const float* mb = m_prev + goff;
#pragma unroll
        for (int k = 0; k < 4; ++k)
            load_lds16(mb + (size_t)k * 16 * H_SZ + lsrc,
                       (char*)eM + w * 4096 + k * 1024);
    }
    const int j = jbase + fr;                          // 0..1023
    const float bvi = bi[j], bvf = bfv[j], bvo = bo[j], bvz = bz[j];

    __syncthreads();           // drains staging + m-panel + bias loads
    compute();                 // last K-tile
    __syncthreads();           // all waves' lA/lB reads done -> overlay free

    // ---- c/n panel prefetch into the lA/lB overlay (wave-local) ----------
    {
        const float* cb = c_prev + goff;
        const float* nb = n_prev + goff;
#pragma unroll
        for (int k = 0; k < 4; ++k) {
            load_lds16(cb + (size_t)k * 16 * H_SZ + lsrc,
                       (char*)eC + w * 4096 + k * 1024);
            load_lds16(nb + (size_t)k * 16 * H_SZ + lsrc,
                       (char*)eN + w * 4096 + k * 1024);
        }
    }
    asm volatile("s_waitcnt vmcnt(0)" ::: "memory");   // wave's panels landed

    // ---- fused sLSTM epilogue (LDS panels [64][16] f32 at wave base) -----
    const size_t BH = (size_t)B_SZ * H_SZ;
    const int ebase = w * 1024;                        // float index

#pragma unroll
    for (int mi = 0; mi < 4; ++mi) {
        const int rbase = m0 + wm * 64 + mi * 16 + kq * 4;
        const int erow0 = mi * 16 + kq * 4;            // row within wave panel
#pragma unroll
        for (int r2 = 0; r2 < 4; ++r2) {
            const size_t idx = (size_t)(rbase + r2) * H_SZ + j;
            const int eidx = ebase + (erow0 + r2) * 16 + fr;
            float pi = acc[mi][0][r2] + bvi;
            float pf = acc[mi][1][r2] + bvf;
            float po = acc[mi][2][r2] + bvo;
            float pz = acc[mi][3][r2] + bvz;
            float iv = __expf(pi);
            float fv = rcp_fast(1.0f + __expf(-pf));                   // sigmoid
            float ov = rcp_fast(1.0f + __expf(-po));                   // sigmoid
            float zv = 1.0f - 2.0f * rcp_fast(__expf(2.0f * pz) + 1.0f); // tanh
            float cv = fv * eC[eidx] + iv * zv;
            float nv = fv * eN[eidx] + iv;
            float mv = fmaxf(__logf(fv) + eM[eidx], pi);
            out[idx]          = ov * cv * rcp_fast(nv);                // h
            out[BH + idx]     = cv;                                    // c
            out[3 * BH + idx] = nv;                                    // n
            out[4 * BH + idx] = mv;                                    // m
        }
    }
}

// ---------------------------------------------------------------------------
extern "C" void kernel_launch(void* const* d_in, const int* in_sizes, int n_in,
                              void* d_out, int out_size, void* d_ws, size_t ws_size,
                              hipStream_t stream) {
    const float* x      = (const float*)d_in[0];
    const float* h_prev = (const float*)d_in[1];
    const float* c_prev = (const float*)d_in[2];
    const float* C_prev = (const float*)d_in[3];
    const float* n_prev = (const float*)d_in[4];
    const float* m_prev = (const float*)d_in[5];
    const float* Wz = (const float*)d_in[6];
    const float* bz = (const float*)d_in[7];
    const float* Rz = (const float*)d_in[8];
    const float* Wi = (const float*)d_in[9];
    const float* bi = (const float*)d_in[10];
    const float* Ri = (const float*)d_in[11];
    const float* Wf = (const float*)d_in[12];
    const float* bf = (const float*)d_in[13];
    const float* Rf = (const float*)d_in[14];
    const float* Wo = (const float*)d_in[15];
    const float* bo = (const float*)d_in[16];
    const float* Ro = (const float*)d_in[17];
    float* out = (float*)d_out;

    const size_t BH = (size_t)B_SZ * H_SZ;

    // workspace layout: A_f16 (32MB) | W_f16 (16MB)
    u16* Abuf = (u16*)d_ws;
    u16* Wbuf = (u16*)((char*)d_ws + (size_t)32 * 1024 * 1024);

    convert_AW<<<2048, 256, 0, stream>>>(x, h_prev, Wi, Wf, Wo, Wz,
                                         Ri, Rf, Ro, Rz, C_prev,
                                         Abuf, Wbuf, out + 2 * BH);

    gemm_fused<<<dim3(B_SZ / 128, N4H / 128), 256, 0, stream>>>(
        Abuf, Wbuf, c_prev, n_prev, m_prev, bi, bf, bo, bz, out);
}